// Round 8
// baseline (71.644 us; speedup 1.0000x reference)
//
#include <hip/hip_runtime.h>
#include <float.h>

// EuclideanCodebook R8: barrier-free global-stream GEMM.
// Codebook (512KB f16 hi/lo fragment image) streamed L2->registers directly —
// no LDS staging, no barriers, no vmcnt discipline. 1 wave/SIMD, 64 x-rows
// per wave in registers, tile-level register double-buffer (load lead ~1800cy).
// score = 2*dot - e^2; -e^2 folded via K-extension MFMA (acc-init pass).
// dot via f16 split: (2xh)*eh + (2xl)*eh + (2xh)*el, fp32 accumulate.
// ws: [0: esq 4KB | 4096: e8 planes 32KB | 36864: frag image 512KB]

#define Cdim    128
#define KK8_OFF 4096
#define IMG_OFF 36864

typedef _Float16 f16;
typedef __attribute__((ext_vector_type(8)))  _Float16 f16x8;
typedef __attribute__((ext_vector_type(16))) float    f32x16;

#define MFMA(A, B, C) __builtin_amdgcn_mfma_f32_32x32x16_f16((A), (B), (C), 0, 0, 0)

// ---------------- e_sq pre-pass (exact fp32) ----------------
__global__ __launch_bounds__(256) void esq_kernel(const float* __restrict__ embed,
                                                  float* __restrict__ esq, int K) {
    int gid  = blockIdx.x * blockDim.x + threadIdx.x;
    int code = gid >> 6;
    int lane = threadIdx.x & 63;
    if (code >= K) return;
    float2 v = ((const float2*)(embed + (size_t)code * Cdim))[lane];
    float  s = fmaf(v.x, v.x, v.y * v.y);
    #pragma unroll
    for (int m = 32; m >= 1; m >>= 1) s += __shfl_xor(s, m, 64);
    if (lane == 0) esq[code] = s;
}

__device__ __forceinline__ void cvt8s(float4 a, float4 b, float scale,
                                      f16x8& h, f16x8& lo) {
    float v[8] = {a.x, a.y, a.z, a.w, b.x, b.y, b.z, b.w};
    #pragma unroll
    for (int i = 0; i < 8; ++i) {
        float s = v[i] * scale;
        f16 hh = (f16)s;
        h[i]  = hh;
        lo[i] = (f16)(s - (float)hh);
    }
}

// ---- codebook -> fragment image, tile=32 codes; one thread per (code,slot) ----
// frag addr (kk<8): IMG_OFF + tile*16384 + kk*1024 + lh*512 + lm*16 (lo +8192)
// e8 plane (slot 16/17): KK8_OFF + tile*1024 + lh*512 + lm*16, [-e2h,-e2l] @ lh==0
__global__ __launch_bounds__(256) void bconv_kernel(const float* __restrict__ embed,
                                                    const float* __restrict__ esq,
                                                    char* __restrict__ ws) {
    int t    = blockIdx.x * 256 + threadIdx.x;   // 18432 threads
    int code = t / 18;
    int slot = t % 18;
    int kk   = slot >> 1;
    int lh   = slot & 1;
    int tile = code >> 5, lm = code & 31;
    if (kk < 8) {
        const float4* p = (const float4*)(embed + (size_t)code * Cdim + kk * 16 + lh * 8);
        f16x8 h, lo;
        cvt8s(p[0], p[1], 1.0f, h, lo);
        size_t base = (size_t)IMG_OFF + (size_t)tile * 16384 + kk * 1024 + lh * 512 + lm * 16;
        *(f16x8*)(ws + base)        = h;
        *(f16x8*)(ws + base + 8192) = lo;
    } else {
        f16x8 f = {};
        if (lh == 0) {
            float e2 = esq[code];
            f16 e2h = (f16)e2;
            f[0] = -e2h;
            f[1] = (f16)-(e2 - (float)e2h);
        }
        *(f16x8*)(ws + (size_t)KK8_OFF + (size_t)tile * 1024 + lh * 512 + lm * 16) = f;
    }
}

// load tile T's fragments into named regs (H[8], L[8], E8)
#define LOADT(T, H, L, E8) do {                                          \
    const char* _p = img + (size_t)(T) * 16384;                          \
    _Pragma("unroll")                                                    \
    for (int _k = 0; _k < 8; ++_k) {                                     \
        H[_k] = *(const f16x8*)(_p + _k * 1024);                         \
        L[_k] = *(const f16x8*)(_p + 8192 + _k * 1024);                  \
    }                                                                    \
    E8 = *(const f16x8*)(e8p + (size_t)(T) * 1024);                      \
} while (0)

// compute + score tile T from named regs
#define PROCT(T, H, L, E8) do {                                          \
    f32x16 _a0, _a1;                                                     \
    _Pragma("unroll")                                                    \
    for (int _r = 0; _r < 16; ++_r) { _a0[_r] = 0.f; _a1[_r] = 0.f; }    \
    _a0 = MFMA(E8, bconst, _a0);      /* acc init = -e^2 */              \
    _a1 = MFMA(E8, bconst, _a1);                                         \
    _Pragma("unroll")                                                    \
    for (int _k = 0; _k < 8; ++_k) {                                     \
        _a0 = MFMA(H[_k], bxh0[_k], _a0);                                \
        _a1 = MFMA(H[_k], bxh1[_k], _a1);                                \
        _a0 = MFMA(L[_k], bxh0[_k], _a0);                                \
        _a1 = MFMA(L[_k], bxh1[_k], _a1);                                \
        _a0 = MFMA(H[_k], bxl0[_k], _a0);                                \
        _a1 = MFMA(H[_k], bxl1[_k], _a1);                                \
    }                                                                    \
    const int _cb = (T) * 32 + 4 * lh;                                   \
    _Pragma("unroll")                                                    \
    for (int _r = 0; _r < 16; ++_r) {                                    \
        const int _code = _cb + (_r & 3) + 8 * (_r >> 2);                \
        float _s0 = _a0[_r], _s1 = _a1[_r];                              \
        if (_s0 > best0) { best0 = _s0; bidx0 = _code; }                 \
        if (_s1 > best1) { best1 = _s1; bidx1 = _code; }                 \
    }                                                                    \
} while (0)

__global__ __launch_bounds__(256, 1) void vq_kernel(
    const float* __restrict__ x, const float* __restrict__ embed,
    const char* __restrict__ ws, float* __restrict__ outq,
    float* __restrict__ outi) {

    const int tid  = threadIdx.x;
    const int wid  = tid >> 6;
    const int l    = tid & 63;
    const int lm   = l & 31;
    const int lh   = l >> 5;
    const int wrow = (blockIdx.x * 4 + wid) * 64;   // wave owns rows wrow..wrow+63

    // ---- x rows -> B-fragments (2*xh, 2*xl), 2 row-tiles of 32 ----
    f16x8 bxh0[8], bxl0[8], bxh1[8], bxl1[8];
    {
        const float* xr0 = x + (size_t)(wrow + lm) * Cdim + lh * 8;
        const float* xr1 = x + (size_t)(wrow + 32 + lm) * Cdim + lh * 8;
        #pragma unroll
        for (int kk = 0; kk < 8; ++kk) {
            float4 a0 = *(const float4*)(xr0 + kk * 16);
            float4 a1 = *(const float4*)(xr0 + kk * 16 + 4);
            cvt8s(a0, a1, 2.0f, bxh0[kk], bxl0[kk]);
            float4 b0 = *(const float4*)(xr1 + kk * 16);
            float4 b1 = *(const float4*)(xr1 + kk * 16 + 4);
            cvt8s(b0, b1, 2.0f, bxh1[kk], bxl1[kk]);
        }
    }

    // x~ extension: k=0,1 -> 1,1 (lh==0 lanes) for the -e^2 fold pass
    f16x8 bconst = {};
    if (lh == 0) { bconst[0] = (f16)1.f; bconst[1] = (f16)1.f; }

    const char* img = ws + IMG_OFF + (size_t)l * 16;
    const char* e8p = ws + KK8_OFF + (size_t)l * 16;

    float best0 = -FLT_MAX, best1 = -FLT_MAX;
    int   bidx0 = 0,        bidx1 = 0;

    f16x8 Ah[8], Al[8], Ae8;
    f16x8 Bh[8], Bl[8], Be8;

    LOADT(0, Ah, Al, Ae8);

    #pragma unroll 1
    for (int t = 0; t < 32; t += 2) {
        LOADT(t + 1, Bh, Bl, Be8);      // prefetch odd tile
        PROCT(t, Ah, Al, Ae8);
        if (t + 2 < 32) LOADT(t + 2, Ah, Al, Ae8);   // prefetch next even tile
        PROCT(t + 1, Bh, Bl, Be8);
        __builtin_amdgcn_s_barrier();   // phase-lock 4 waves for L1 sharing
    }

    // ---- merge lh halves (same rows, different code subsets) ----
    {
        float v; int vi;
        v = __shfl_xor(best0, 32, 64); vi = __shfl_xor(bidx0, 32, 64);
        if (v > best0 || (v == best0 && vi < bidx0)) { best0 = v; bidx0 = vi; }
        v = __shfl_xor(best1, 32, 64); vi = __shfl_xor(bidx1, 32, 64);
        if (v > best1 || (v == best1 && vi < bidx1)) { best1 = v; bidx1 = vi; }
    }

    // ---- write indices (lane lm holds rows wrow+lm, wrow+32+lm) ----
    if (lh == 0) {
        outi[wrow + lm]      = (float)bidx0;
        outi[wrow + 32 + lm] = (float)bidx1;
    }

    // ---- gather quantized = embed[winner] (readlane, no LDS) ----
    #pragma unroll
    for (int r = 0; r < 32; ++r) {
        int i0 = __builtin_amdgcn_readlane(bidx0, r);
        int i1 = __builtin_amdgcn_readlane(bidx1, r);
        float2 v0 = ((const float2*)(embed + (size_t)i0 * Cdim))[l];
        float2 v1 = ((const float2*)(embed + (size_t)i1 * Cdim))[l];
        ((float2*)(outq + (size_t)(wrow + r) * Cdim))[l]      = v0;
        ((float2*)(outq + (size_t)(wrow + 32 + r) * Cdim))[l] = v1;
    }
}

extern "C" void kernel_launch(void* const* d_in, const int* in_sizes, int n_in,
                              void* d_out, int out_size, void* d_ws, size_t ws_size,
                              hipStream_t stream) {
    const float* x     = (const float*)d_in[0];
    const float* embed = (const float*)d_in[1];
    const int M = in_sizes[0] / Cdim;   // 65536
    const int K = in_sizes[1] / Cdim;   // 1024
    float* outq = (float*)d_out;
    float* outi = outq + (size_t)M * Cdim;

    esq_kernel <<<K / 4, 256, 0, stream>>>(embed, (float*)d_ws, K);
    bconv_kernel<<<72, 256, 0, stream>>>(embed, (const float*)d_ws, (char*)d_ws);
    vq_kernel  <<<M / 256, 256, 0, stream>>>(x, embed, (const char*)d_ws,
                                             outq, outi);
}

// Round 9
// 61.437 us; speedup vs baseline: 1.1661x; 1.1661x over previous
//
#include <hip/hip_runtime.h>
#include <float.h>

// EuclideanCodebook R9: 16x16x32 f16-split MFMA with 8 INDEPENDENT f32x4
// accumulator chains (the R4-R8 2-chain dep-latency wall fix).
// R7 shell: 256-thr blocks, wave-pair shares 64 x-rows / splits codes,
// CH=64 DMA dbuf (linear global_load_lds, vmcnt(8)), 2 blocks/CU.
// Codebook image in per-fragment WAVE-LINEAR order (lane l -> byte l*16):
// identity LDS read pattern = conflict-free. score = 2*dot - e^2.
// dot via f16 split: (2xh)*eh + (2xl)*eh + (2xh)*el, fp32 accumulate.
// ws: [0: esq 4KB | 4096: frag image 512KB]

#define Cdim        128
#define KCODES      1024
#define CH          64
#define NCH         16
#define BROWS       128       // 2 row-groups x 64 rows; wave pair splits codes
#define THREADS     256
#define IMG_OFF     4096
#define CHUNK_BYTES 32768     // [hi: (ctg*4+ks)*1KB x16 | lo: +16KB]

typedef _Float16 f16;
typedef __attribute__((ext_vector_type(8))) _Float16 f16x8;
typedef __attribute__((ext_vector_type(4))) float    f32x4;

#define MFMA16(A, B, C) __builtin_amdgcn_mfma_f32_16x16x32_f16((A), (B), (C), 0, 0, 0)

// ---------------- e_sq pre-pass (exact fp32) ----------------
__global__ __launch_bounds__(256) void esq_kernel(const float* __restrict__ embed,
                                                  float* __restrict__ esq, int K) {
    int gid  = blockIdx.x * blockDim.x + threadIdx.x;
    int code = gid >> 6;
    int lane = threadIdx.x & 63;
    if (code >= K) return;
    float2 v = ((const float2*)(embed + (size_t)code * Cdim))[lane];
    float  s = fmaf(v.x, v.x, v.y * v.y);
    #pragma unroll
    for (int m = 32; m >= 1; m >>= 1) s += __shfl_xor(s, m, 64);
    if (lane == 0) esq[code] = s;
}

__device__ __forceinline__ void cvt8s(float4 a, float4 b, float scale,
                                      f16x8& h, f16x8& lo) {
    float v[8] = {a.x, a.y, a.z, a.w, b.x, b.y, b.z, b.w};
    #pragma unroll
    for (int i = 0; i < 8; ++i) {
        float s = v[i] * scale;
        f16 hh = (f16)s;
        h[i]  = hh;
        lo[i] = (f16)(s - (float)hh);
    }
}

// ---- codebook -> 16x16x32-fragment image, wave-linear lane order ----
// A-frag (16x16x32): lane l holds e[code = base + (l&15)][k = ks*32+(l>>4)*8 ..+8]
// hi addr: IMG_OFF + ch*32768 + (ctg*4+ks)*1024 + ((l>>4)*16 + (l&15))*16; lo +16384
__global__ __launch_bounds__(256) void bconv_kernel(const float* __restrict__ embed,
                                                    char* __restrict__ ws) {
    int t    = blockIdx.x * 256 + threadIdx.x;   // 16384 threads
    int code = t >> 4;
    int seg  = t & 15;
    int ks   = seg >> 2;
    int kseg = seg & 3;
    int ch = code >> 6, ctg = (code >> 4) & 3, lr = code & 15;
    const float4* p = (const float4*)(embed + (size_t)code * Cdim + ks * 32 + kseg * 8);
    f16x8 h, lo;
    cvt8s(p[0], p[1], 1.0f, h, lo);
    size_t base = (size_t)IMG_OFF + (size_t)ch * CHUNK_BYTES
                + (ctg * 4 + ks) * 1024 + (kseg * 16 + lr) * 16;
    *(f16x8*)(ws + base)         = h;
    *(f16x8*)(ws + base + 16384) = lo;
}

// ---------------- async global->LDS 16B ----------------
__device__ __forceinline__ void gll16(const void* g, void* l) {
    __builtin_amdgcn_global_load_lds(
        (const __attribute__((address_space(1))) unsigned int*)g,
        (__attribute__((address_space(3))) unsigned int*)l, 16, 0, 0);
}

__global__ __launch_bounds__(THREADS, 2) void vq_kernel(
    const float* __restrict__ x, const float* __restrict__ embed,
    const char* __restrict__ ws, float* __restrict__ outq,
    float* __restrict__ outi) {

    __shared__ __align__(16) char  Bb[2][CHUNK_BYTES];   // 64KB dbuf
    __shared__ __align__(16) float esq_lds[KCODES];      // 4KB
    __shared__ float mrg_v[2][BROWS];
    __shared__ int   mrg_i[2][BROWS];
    __shared__ int   winners[BROWS];

    const int tid  = threadIdx.x;
    const int wid  = tid >> 6;          // wave 0..3
    const int l    = tid & 63;
    const int lr   = l & 15;            // x-row within 16-tile / code within frag
    const int lg   = l >> 4;            // k-seg (inputs) / code-subrow (outputs)
    const int wr   = wid & 1;           // row group (64 rows)
    const int nt   = wid >> 1;          // code half of each chunk
    const int row0 = blockIdx.x * BROWS;

    // ---- prologue DMA: chunk 0 (8KB/wave) + esq (1KB/wave) ----
    {
        const char* src = ws + IMG_OFF + wid * 8192 + (size_t)l * 16;
        char*       dst = &Bb[0][wid * 8192];
        #pragma unroll
        for (int i = 0; i < 8; ++i) gll16(src + i * 1024, dst + i * 1024);
        gll16(ws + wid * 1024 + (size_t)l * 16, (char*)esq_lds + wid * 1024);
    }

    // ---- x rows -> B-fragments (2*xh, 2*xl): bx[rt][ks], rows wr*64+rt*16+lr ----
    f16x8 bxh[4][4], bxl[4][4];
    #pragma unroll
    for (int rt = 0; rt < 4; ++rt) {
        const float* xr = x + (size_t)(row0 + wr * 64 + rt * 16 + lr) * Cdim + lg * 8;
        #pragma unroll
        for (int ks = 0; ks < 4; ++ks) {
            float4 v0 = *(const float4*)(xr + ks * 32);
            float4 v1 = *(const float4*)(xr + ks * 32 + 4);
            cvt8s(v0, v1, 2.0f, bxh[rt][ks], bxl[rt][ks]);
        }
    }

    float best[4];
    int   bidx[4];
    #pragma unroll
    for (int rt = 0; rt < 4; ++rt) { best[rt] = -FLT_MAX; bidx[rt] = 0; }

    #pragma unroll 1
    for (int ch = 0; ch < NCH; ++ch) {
        const int cur = ch & 1, nxt = cur ^ 1;

        __builtin_amdgcn_s_barrier();            // all done reading Bb[nxt]
        if (ch + 1 < NCH) {
            const char* src = ws + IMG_OFF + (size_t)(ch + 1) * CHUNK_BYTES
                            + wid * 8192 + (size_t)l * 16;
            char* dst = &Bb[nxt][wid * 8192];
            #pragma unroll
            for (int i = 0; i < 8; ++i) gll16(src + i * 1024, dst + i * 1024);
            asm volatile("s_waitcnt vmcnt(8)" ::: "memory");   // chunk ch staged
        } else {
            asm volatile("s_waitcnt vmcnt(0)" ::: "memory");
        }
        __builtin_amdgcn_s_barrier();            // chunk ch visible block-wide

        // 8 independent accumulator chains: acc[ct][rt]
        f32x4 acc[2][4];
        #pragma unroll
        for (int ct = 0; ct < 2; ++ct)
            #pragma unroll
            for (int rt = 0; rt < 4; ++rt)
                acc[ct][rt] = (f32x4){0.f, 0.f, 0.f, 0.f};

        const char* bb = &Bb[cur][(size_t)l * 16];

        #pragma unroll
        for (int ks = 0; ks < 4; ++ks) {
            // A-frags (codebook): identity lane pattern, conflict-free
            f16x8 eh0 = *(const f16x8*)(bb + ((nt * 2 + 0) * 4 + ks) * 1024);
            f16x8 el0 = *(const f16x8*)(bb + ((nt * 2 + 0) * 4 + ks) * 1024 + 16384);
            f16x8 eh1 = *(const f16x8*)(bb + ((nt * 2 + 1) * 4 + ks) * 1024);
            f16x8 el1 = *(const f16x8*)(bb + ((nt * 2 + 1) * 4 + ks) * 1024 + 16384);

            __builtin_amdgcn_s_setprio(1);
            // pass 1: eh * 2xh   (same-acc reuse distance = 8 MFMAs)
            #pragma unroll
            for (int rt = 0; rt < 4; ++rt) acc[0][rt] = MFMA16(eh0, bxh[rt][ks], acc[0][rt]);
            #pragma unroll
            for (int rt = 0; rt < 4; ++rt) acc[1][rt] = MFMA16(eh1, bxh[rt][ks], acc[1][rt]);
            // pass 2: eh * 2xl
            #pragma unroll
            for (int rt = 0; rt < 4; ++rt) acc[0][rt] = MFMA16(eh0, bxl[rt][ks], acc[0][rt]);
            #pragma unroll
            for (int rt = 0; rt < 4; ++rt) acc[1][rt] = MFMA16(eh1, bxl[rt][ks], acc[1][rt]);
            // pass 3: el * 2xh
            #pragma unroll
            for (int rt = 0; rt < 4; ++rt) acc[0][rt] = MFMA16(el0, bxh[rt][ks], acc[0][rt]);
            #pragma unroll
            for (int rt = 0; rt < 4; ++rt) acc[1][rt] = MFMA16(el1, bxh[rt][ks], acc[1][rt]);
            __builtin_amdgcn_s_setprio(0);
        }

        // scoring: s = 2*dot - e^2; lane's codes = cb + lg*4 + j (ascending)
        #pragma unroll
        for (int ct = 0; ct < 2; ++ct) {
            const int cb = ch * CH + (nt * 2 + ct) * 16 + lg * 4;
            float4 e4 = *(const float4*)&esq_lds[cb];
            #pragma unroll
            for (int rt = 0; rt < 4; ++rt) {
                #pragma unroll
                for (int j = 0; j < 4; ++j) {
                    float s = acc[ct][rt][j] - ((const float*)&e4)[j];
                    if (s > best[rt]) { best[rt] = s; bidx[rt] = cb + j; }
                }
            }
        }
    }

    // ---- reduce over lg (lanes lr, lr+16, lr+32, lr+48 share each row) ----
    #pragma unroll
    for (int rt = 0; rt < 4; ++rt) {
        float bs = best[rt]; int bi = bidx[rt];
        #pragma unroll
        for (int m = 16; m <= 32; m <<= 1) {
            float vs = __shfl_xor(bs, m, 64);
            int   vi = __shfl_xor(bi, m, 64);
            if (vs > bs || (vs == bs && vi < bi)) { bs = vs; bi = vi; }
        }
        if (lg == 0) {
            mrg_v[nt][wr * 64 + rt * 16 + lr] = bs;
            mrg_i[nt][wr * 64 + rt * 16 + lr] = bi;
        }
    }
    __syncthreads();
    if (tid < BROWS) {
        float v0 = mrg_v[0][tid]; int i0 = mrg_i[0][tid];
        float v1 = mrg_v[1][tid]; int i1 = mrg_i[1][tid];
        int bi = (v1 > v0 || (v1 == v0 && i1 < i0)) ? i1 : i0;
        winners[tid] = bi;
        outi[row0 + tid] = (float)bi;
    }
    __syncthreads();

    // ---- gather quantized = embed[winner] (exact fp32 copy) ----
    #pragma unroll
    for (int i = 0; i < 16; ++i) {
        int pos = i * THREADS + tid;
        int r = pos >> 5, c4 = pos & 31;
        int idx = winners[r];
        float4 v = ((const float4*)(embed + (size_t)idx * Cdim))[c4];
        ((float4*)(outq + (size_t)(row0 + r) * Cdim))[c4] = v;
    }
}

extern "C" void kernel_launch(void* const* d_in, const int* in_sizes, int n_in,
                              void* d_out, int out_size, void* d_ws, size_t ws_size,
                              hipStream_t stream) {
    const float* x     = (const float*)d_in[0];
    const float* embed = (const float*)d_in[1];
    const int M = in_sizes[0] / Cdim;   // 65536
    const int K = in_sizes[1] / Cdim;   // 1024
    float* outq = (float*)d_out;
    float* outi = outq + (size_t)M * Cdim;

    esq_kernel <<<K / 4, 256, 0, stream>>>(embed, (float*)d_ws, K);
    bconv_kernel<<<64, 256, 0, stream>>>(embed, (char*)d_ws);
    vq_kernel  <<<M / BROWS, THREADS, 0, stream>>>(x, embed, (const char*)d_ws,
                                                   outq, outi);
}